// Round 5
// baseline (358.167 us; speedup 1.0000x reference)
//
#include <hip/hip_runtime.h>

#define OUTSZ 7
#define SS 14               // sample rows/cols per box
#define NS 196              // samples per box
#define C_BAND 256
#define H_BAND 100
#define H_FULL 200
#define W_FULL 200
#define POS (H_FULL*W_FULL)       // 40000 positions per batch image
#define NBOX 512
#define FEATT_OFF 4096            // perm occupies first 2048 B of d_ws

// ---------------- sort: boxes by (batch, y1) for L2 locality ----------------
__global__ __launch_bounds__(256) void sort_boxes_kernel(
    const float* __restrict__ boxes, int* __restrict__ perm)
{
    __shared__ int keys[NBOX];
    __shared__ int vals[NBOX];
    const int tid = threadIdx.x;
    for (int i = tid; i < NBOX; i += 256) {
        const int n = (int)boxes[i*5 + 0];
        const int y = (int)boxes[i*5 + 2];
        keys[i] = n * 256 + y;
        vals[i] = i;
    }
    __syncthreads();
    for (int size = 2; size <= NBOX; size <<= 1) {
        for (int stride = size >> 1; stride > 0; stride >>= 1) {
            const int i = (tid / stride) * (stride * 2) + (tid % stride);
            const int j = i + stride;
            const bool up = ((i & size) == 0);
            const int ki = keys[i], kj = keys[j];
            if ((ki > kj) == up) {
                keys[i] = kj; keys[j] = ki;
                const int v = vals[i]; vals[i] = vals[j]; vals[j] = v;
            }
            __syncthreads();
        }
    }
    for (int i = tid; i < NBOX; i += 256) perm[i] = vals[i];
}

// ---------------- pass 1: NCHW -> NHWC transpose (streaming) ----------------
// feat  [4][256][40000]  ->  featT [4][40000][256]
__global__ __launch_bounds__(256) void transpose_kernel(
    const float* __restrict__ feat, float* __restrict__ featT)
{
    __shared__ float tile[64][65];   // +1 pad: transposed reads conflict-free
    const int b    = blockIdx.x;     // 10000 = 4 n * 4 cgroups * 625 pos-tiles
    const int pt   = b % 625;
    const int cg   = (b / 625) & 3;
    const int n    = b / 2500;
    const int c0   = cg * 64;
    const int pos0 = pt * 64;
    const int tid  = threadIdx.x;

    {   // read 64c x 64pos tile, float4 along pos (coalesced)
        const int xq = tid & 15;
        const int cb = tid >> 4;
        const float* src = feat + (size_t)(n * C_BAND + c0) * POS + pos0;
        #pragma unroll
        for (int r = 0; r < 4; ++r) {
            const int ci = cb + (r << 4);
            const float4 v = *(const float4*)(src + (size_t)ci * POS + (xq << 2));
            tile[ci][(xq<<2)+0] = v.x;
            tile[ci][(xq<<2)+1] = v.y;
            tile[ci][(xq<<2)+2] = v.z;
            tile[ci][(xq<<2)+3] = v.w;
        }
    }
    __syncthreads();
    {   // write transposed, float4 along c (coalesced)
        const int cq = tid & 15;
        const int pb = tid >> 4;
        float* dst = featT + ((size_t)n * POS + pos0) * C_BAND + c0;
        #pragma unroll
        for (int r = 0; r < 4; ++r) {
            const int pi = pb + (r << 4);
            float4 v;
            v.x = tile[(cq<<2)+0][pi];
            v.y = tile[(cq<<2)+1][pi];
            v.z = tile[(cq<<2)+2][pi];
            v.w = tile[(cq<<2)+3][pi];
            *(float4*)(dst + (size_t)pi * C_BAND + (cq<<2)) = v;
        }
    }
}

// ---------------- pass 2: ROIAlign gather, lanes = channels ----------------
__global__ __launch_bounds__(256) void roi_gather_kernel(
    const float* __restrict__ featT,  // [4][200][200][256]
    const float* __restrict__ boxes,
    const int*   __restrict__ perm,
    float* __restrict__ out)          // [512][512][49]
{
    __shared__ int    s_off[NS];      // byte offset of (yb,xb) in [y][x][c] grid
    __shared__ float4 s_w[NS];        // folded corner weights
    __shared__ float  s_tile[4][64*49];  // per-wave output tile [c][bin]

    const int b    = blockIdx.x;      // 1024
    const int xcd  = b & 7;           // consecutive sorted boxes stay on one XCD
    const int unit = xcd * 128 + (b >> 3);
    const int band = unit & 1;
    const int k    = perm[unit >> 1];
    const int tid  = threadIdx.x;
    const int lane = tid & 63;
    const int wv   = tid >> 6;

    const float bxf = boxes[k*5 + 0];
    const float x1  = boxes[k*5 + 1];
    const float y1  = boxes[k*5 + 2];
    const float x2  = boxes[k*5 + 3];
    const float y2  = boxes[k*5 + 4];
    const int   n   = (int)bxf;

    const float bin_w = fmaxf(x2 - x1, 1.0f) * (1.0f / 7.0f);
    const float bin_h = fmaxf(y2 - y1, 1.0f) * (1.0f / 7.0f);

    if (tid < NS) {
        const int sy = tid / SS;
        const int sx = tid - sy * SS;
        float y = y1 + ((float)(sy>>1) + ((float)(sy&1) + 0.5f) * 0.5f) * bin_h;
        float x = x1 + ((float)(sx>>1) + ((float)(sx&1) + 0.5f) * 0.5f) * bin_w;
        const bool valid = (y >= -1.0f) && (y <= 100.0f) &&
                           (x >= -1.0f) && (x <= 200.0f);
        y = fminf(fmaxf(y, 0.f), 99.f);
        x = fminf(fmaxf(x, 0.f), 199.f);
        const int y_lo = (int)floorf(y);
        const int x_lo = (int)floorf(x);
        const float ly = y - (float)y_lo;
        const float lx = x - (float)x_lo;
        const float hy = 1.f - ly, hx = 1.f - lx;
        // clamp-fold both axes so corners are always (yb,yb+1)x(xb,xb+1)
        const int yb = min(y_lo, H_BAND - 2);
        const int xb = min(x_lo, W_FULL - 2);
        float wy0, wy1, wx0, wx1;
        if (y_lo == yb) { wy0 = hy;  wy1 = ly; } else { wy0 = 0.f; wy1 = hy + ly; }
        if (x_lo == xb) { wx0 = hx;  wx1 = lx; } else { wx0 = 0.f; wx1 = hx + lx; }
        const float vs = valid ? 1.f : 0.f;
        s_off[tid] = (((band * H_BAND + yb) * W_FULL) + xb) * (C_BAND * 4);
        s_w[tid] = make_float4(wy0*wx0*vs, wy0*wx1*vs, wy1*wx0*vs, wy1*wx1*vs);
    }
    __syncthreads();

    // this wave's channel group: base at (n, y=0, x=0, c = wv*64 + lane)
    const char* base = (const char*)(featT + (size_t)n * POS * C_BAND
                                           + (wv << 6) + lane);
    const int ROWB = W_FULL * C_BAND * 4;   // bytes per y step

    float* tl = s_tile[wv];
    for (int bin = 0; bin < 49; ++bin) {
        const int ph = bin / 7;
        const int pw = bin - ph * 7;
        const int s00 = (ph * 2) * SS + pw * 2;
        float acc = 0.f;
        #pragma unroll
        for (int iy = 0; iy < 2; ++iy) {
            #pragma unroll
            for (int ix = 0; ix < 2; ++ix) {
                const int s = s00 + iy * SS + ix;
                const float4 w = s_w[s];                   // wave-uniform
                const char* p0 = base + s_off[s];          // coalesced across lanes
                const char* p1 = p0 + ROWB;
                const float v00 = *(const float*)(p0);
                const float v01 = *(const float*)(p0 + C_BAND*4);
                const float v10 = *(const float*)(p1);
                const float v11 = *(const float*)(p1 + C_BAND*4);
                acc += w.x*v00 + w.y*v01 + w.z*v10 + w.w*v11;
            }
        }
        tl[lane * 49 + bin] = acc * 0.25f;   // stride 49 (odd): conflict-free
    }
    __syncthreads();

    // coalesced write-out: tile layout [c][bin] == out slice linear order,
    // so dst[o] = tl[o] for o in [0,3136)
    float* dst = out + ((size_t)k * (2*C_BAND) + band * C_BAND + (wv << 6)) * 49;
    #pragma unroll
    for (int m = 0; m < 49; ++m) {
        dst[(m << 6) + lane] = tl[(m << 6) + lane];
    }
}

// ---------------- fallback (R2 kernel) if workspace too small ----------------
#define PLANE (2*H_BAND*W_FULL)
#define CCHUNK 64
__global__ __launch_bounds__(256) void roi_align_fallback(
    const float* __restrict__ feat, const float* __restrict__ boxes,
    const int* __restrict__ perm, float* __restrict__ out)
{
    __shared__ int    f_i0[NS];
    __shared__ int    f_i1[NS];
    __shared__ float4 f_w[NS];
    const int b     = blockIdx.x;
    const int jj    = b & 7;
    const int chunk = jj & 3;
    const int band  = jj >> 2;
    const int k     = perm[b >> 3];
    const int tid   = threadIdx.x;
    const float bxf = boxes[k*5+0], x1 = boxes[k*5+1], y1 = boxes[k*5+2];
    const float x2  = boxes[k*5+3], y2 = boxes[k*5+4];
    const int   n   = (int)bxf;
    const float bin_w = fmaxf(x2 - x1, 1.0f) * (1.0f/7.0f);
    const float bin_h = fmaxf(y2 - y1, 1.0f) * (1.0f/7.0f);
    if (tid < NS) {
        const int sy = tid / SS, sx = tid - (tid / SS) * SS;
        float y = y1 + ((float)(sy>>1) + ((float)(sy&1) + 0.5f) * 0.5f) * bin_h;
        float x = x1 + ((float)(sx>>1) + ((float)(sx&1) + 0.5f) * 0.5f) * bin_w;
        const bool valid = (y >= -1.f) && (y <= 100.f) && (x >= -1.f) && (x <= 200.f);
        y = fminf(fmaxf(y, 0.f), 99.f);
        x = fminf(fmaxf(x, 0.f), 199.f);
        const int y_lo = (int)floorf(y), x_lo = (int)floorf(x);
        const int y_hi = min(y_lo + 1, H_BAND - 1);
        const float ly = y - (float)y_lo, lx = x - (float)x_lo;
        const float hy = 1.f - ly, hx = 1.f - lx;
        const int xb = min(x_lo, W_FULL - 2);
        float w0, w1;
        if (x_lo == xb) { w0 = hx; w1 = lx; } else { w0 = 0.f; w1 = hx + lx; }
        const float vs = valid ? 1.f : 0.f;
        f_i0[tid] = y_lo * W_FULL + xb;
        f_i1[tid] = y_hi * W_FULL + xb;
        f_w[tid] = make_float4(hy*w0*vs, hy*w1*vs, ly*w0*vs, ly*w1*vs);
    }
    __syncthreads();
    const int c0 = chunk * CCHUNK;
    const float* fbase = feat + (size_t)(n * C_BAND + c0) * PLANE
                              + (size_t)band * (H_BAND * W_FULL);
    float* obase = out + ((size_t)k * (2*C_BAND) + (size_t)band * C_BAND + c0) * 49;
    for (int o = tid; o < CCHUNK * 49; o += 256) {
        const int c = o / 49, bin = o - (o / 49) * 49;
        const int ph = bin / 7, pw = bin - (bin / 7) * 7;
        const float* fc = fbase + (size_t)c * PLANE;
        const int s00 = (ph * 2) * SS + pw * 2;
        float acc = 0.f;
        #pragma unroll
        for (int iy = 0; iy < 2; ++iy)
        #pragma unroll
        for (int ix = 0; ix < 2; ++ix) {
            const int s = s00 + iy * SS + ix;
            const float4 w = f_w[s];
            const float2 a = *(const float2*)(fc + f_i0[s]);
            const float2 d = *(const float2*)(fc + f_i1[s]);
            acc += w.x * a.x + w.y * a.y + w.z * d.x + w.w * d.y;
        }
        obase[o] = acc * 0.25f;
    }
}

extern "C" void kernel_launch(void* const* d_in, const int* in_sizes, int n_in,
                              void* d_out, int out_size, void* d_ws, size_t ws_size,
                              hipStream_t stream) {
    const float* feat  = (const float*)d_in[0];   // [4,256,200,200] f32
    const float* boxes = (const float*)d_in[1];   // [512,5] f32
    float* out = (float*)d_out;                   // [512,512,7,7] f32
    int* perm = (int*)d_ws;                       // 512 ints = 2048 B

    sort_boxes_kernel<<<1, 256, 0, stream>>>(boxes, perm);

    const size_t needT = FEATT_OFF + (size_t)4 * POS * C_BAND * sizeof(float);
    if (ws_size >= needT) {
        float* featT = (float*)((char*)d_ws + FEATT_OFF);
        transpose_kernel<<<10000, 256, 0, stream>>>(feat, featT);
        roi_gather_kernel<<<1024, 256, 0, stream>>>(featT, boxes, perm, out);
    } else {
        roi_align_fallback<<<NBOX * 8, 256, 0, stream>>>(feat, boxes, perm, out);
    }
}

// Round 6
// 292.936 us; speedup vs baseline: 1.2227x; 1.2227x over previous
//
#include <hip/hip_runtime.h>

#define SS 14               // sample rows/cols per box
#define NS 196              // samples per box
#define C_BAND 256
#define H_BAND 100
#define H_FULL 200
#define W_FULL 200
#define POS (H_FULL*W_FULL)       // 40000 positions per batch image
#define NBOX 512
#define FEATT_OFF 4096            // perm occupies first 2048 B of d_ws

__device__ __forceinline__ unsigned short f2bf(float f) {   // RNE f32->bf16
    unsigned int u = __builtin_bit_cast(unsigned int, f);
    u = (u + 0x7fffu + ((u >> 16) & 1u)) >> 16;
    return (unsigned short)u;
}
__device__ __forceinline__ float bf2f(unsigned short h) {
    return __builtin_bit_cast(float, ((unsigned int)h) << 16);
}

// ------------- pass 1: NCHW -> NHWC bf16 transpose; block 0 also sorts -------------
// feat [4][256][40000] f32  ->  featT [4][40000][256] bf16
__global__ __launch_bounds__(256) void transpose_sort_kernel(
    const float* __restrict__ feat, unsigned short* __restrict__ featT,
    const float* __restrict__ boxes, int* __restrict__ perm)
{
    __shared__ float tile[64][65];   // +1 pad
    __shared__ int keys[NBOX];
    __shared__ int vals[NBOX];

    const int b    = blockIdx.x;     // 10000 = 4n * 4cg * 625 pos-tiles
    const int pt   = b % 625;
    const int cg   = (b / 625) & 3;
    const int n    = b / 2500;
    const int c0   = cg * 64;
    const int pos0 = pt * 64;
    const int tid  = threadIdx.x;

    {   // read 64c x 64pos tile, float4 along pos (coalesced)
        const int xq = tid & 15;
        const int cb = tid >> 4;
        const float* src = feat + (size_t)(n * C_BAND + c0) * POS + pos0;
        #pragma unroll
        for (int r = 0; r < 4; ++r) {
            const int ci = cb + (r << 4);
            const float4 v = *(const float4*)(src + (size_t)ci * POS + (xq << 2));
            tile[ci][(xq<<2)+0] = v.x;
            tile[ci][(xq<<2)+1] = v.y;
            tile[ci][(xq<<2)+2] = v.z;
            tile[ci][(xq<<2)+3] = v.w;
        }
    }
    __syncthreads();
    {   // write transposed bf16, ushort4 (8B) along c (coalesced)
        const int cq = tid & 15;
        const int pb = tid >> 4;
        unsigned short* dst = featT + ((size_t)n * POS + pos0) * C_BAND + c0;
        #pragma unroll
        for (int r = 0; r < 4; ++r) {
            const int pi = pb + (r << 4);
            ushort4 v;
            v.x = f2bf(tile[(cq<<2)+0][pi]);
            v.y = f2bf(tile[(cq<<2)+1][pi]);
            v.z = f2bf(tile[(cq<<2)+2][pi]);
            v.w = f2bf(tile[(cq<<2)+3][pi]);
            *(ushort4*)(dst + (size_t)pi * C_BAND + (cq<<2)) = v;
        }
    }

    if (b == 0) {   // box sort hidden under the other 9999 transpose blocks
        for (int i = tid; i < NBOX; i += 256) {
            const int bn = (int)boxes[i*5 + 0];
            const int y  = (int)boxes[i*5 + 2];
            keys[i] = bn * 256 + y;
            vals[i] = i;
        }
        __syncthreads();
        for (int size = 2; size <= NBOX; size <<= 1) {
            for (int stride = size >> 1; stride > 0; stride >>= 1) {
                const int i = (tid / stride) * (stride * 2) + (tid % stride);
                const int j = i + stride;
                const bool up = ((i & size) == 0);
                const int ki = keys[i], kj = keys[j];
                if ((ki > kj) == up) {
                    keys[i] = kj; keys[j] = ki;
                    const int v = vals[i]; vals[i] = vals[j]; vals[j] = v;
                }
                __syncthreads();
            }
        }
        for (int i = tid; i < NBOX; i += 256) perm[i] = vals[i];
    }
}

// ------------- pass 2: ROIAlign gather, lanes = channels, bf16 reads -------------
__global__ __launch_bounds__(256) void roi_gather_kernel(
    const unsigned short* __restrict__ featT,  // [4][200][200][256] bf16
    const float* __restrict__ boxes,
    const int*   __restrict__ perm,
    float* __restrict__ out)                   // [512][512][49]
{
    __shared__ int    s_off[NS];      // byte offset of (yb,xb) in [y][x][c] grid
    __shared__ float4 s_w[NS];        // folded corner weights
    __shared__ float  s_tile[4][64*49];  // per-wave output tile [c][bin]

    const int b    = blockIdx.x;      // 1024
    const int xcd  = b & 7;           // consecutive sorted boxes stay on one XCD
    const int unit = xcd * 128 + (b >> 3);
    const int band = unit & 1;
    const int k    = perm[unit >> 1];
    const int tid  = threadIdx.x;
    const int lane = tid & 63;
    const int wv   = tid >> 6;

    const float bxf = boxes[k*5 + 0];
    const float x1  = boxes[k*5 + 1];
    const float y1  = boxes[k*5 + 2];
    const float x2  = boxes[k*5 + 3];
    const float y2  = boxes[k*5 + 4];
    const int   n   = (int)bxf;

    const float bin_w = fmaxf(x2 - x1, 1.0f) * (1.0f / 7.0f);
    const float bin_h = fmaxf(y2 - y1, 1.0f) * (1.0f / 7.0f);

    if (tid < NS) {
        const int sy = tid / SS;
        const int sx = tid - sy * SS;
        float y = y1 + ((float)(sy>>1) + ((float)(sy&1) + 0.5f) * 0.5f) * bin_h;
        float x = x1 + ((float)(sx>>1) + ((float)(sx&1) + 0.5f) * 0.5f) * bin_w;
        const bool valid = (y >= -1.0f) && (y <= 100.0f) &&
                           (x >= -1.0f) && (x <= 200.0f);
        y = fminf(fmaxf(y, 0.f), 99.f);
        x = fminf(fmaxf(x, 0.f), 199.f);
        const int y_lo = (int)floorf(y);
        const int x_lo = (int)floorf(x);
        const float ly = y - (float)y_lo;
        const float lx = x - (float)x_lo;
        const float hy = 1.f - ly, hx = 1.f - lx;
        // clamp-fold both axes so corners are always (yb,yb+1)x(xb,xb+1)
        const int yb = min(y_lo, H_BAND - 2);
        const int xb = min(x_lo, W_FULL - 2);
        float wy0, wy1, wx0, wx1;
        if (y_lo == yb) { wy0 = hy;  wy1 = ly; } else { wy0 = 0.f; wy1 = hy + ly; }
        if (x_lo == xb) { wx0 = hx;  wx1 = lx; } else { wx0 = 0.f; wx1 = hx + lx; }
        const float vs = valid ? 1.f : 0.f;
        s_off[tid] = (((band * H_BAND + yb) * W_FULL) + xb) * (C_BAND * 2);
        s_w[tid] = make_float4(wy0*wx0*vs, wy0*wx1*vs, wy1*wx0*vs, wy1*wx1*vs);
    }
    __syncthreads();

    // wave's channel group: base at (n, y=0, x=0, c = wv*64 + lane), bf16
    const char* base = (const char*)featT
        + ((size_t)n * POS * C_BAND + (wv << 6) + lane) * 2;
    const int ROWB  = W_FULL * C_BAND * 2;   // bytes per y step
    const int XSTEP = C_BAND * 2;            // bytes per x step

    float* tl = s_tile[wv];
    for (int bin = 0; bin < 49; ++bin) {
        const int ph = bin / 7;
        const int pw = bin - ph * 7;
        const int s00 = (ph * 2) * SS + pw * 2;
        float acc = 0.f;
        #pragma unroll
        for (int iy = 0; iy < 2; ++iy) {
            #pragma unroll
            for (int ix = 0; ix < 2; ++ix) {
                const int s = s00 + iy * SS + ix;
                const float4 w = s_w[s];                   // wave-uniform
                const char* p0 = base + s_off[s];          // 128B/wave, coalesced
                const char* p1 = p0 + ROWB;
                const float v00 = bf2f(*(const unsigned short*)(p0));
                const float v01 = bf2f(*(const unsigned short*)(p0 + XSTEP));
                const float v10 = bf2f(*(const unsigned short*)(p1));
                const float v11 = bf2f(*(const unsigned short*)(p1 + XSTEP));
                acc += w.x*v00 + w.y*v01 + w.z*v10 + w.w*v11;
            }
        }
        tl[lane * 49 + bin] = acc * 0.25f;   // stride 49 (odd): conflict-free
    }
    __syncthreads();

    // coalesced write-out: tile layout [c][bin] == out slice linear order
    float* dst = out + ((size_t)k * (2*C_BAND) + band * C_BAND + (wv << 6)) * 49;
    #pragma unroll
    for (int m = 0; m < 49; ++m) {
        dst[(m << 6) + lane] = tl[(m << 6) + lane];
    }
}

// ---------------- fallback (R2 kernel, f32 direct) if ws too small ----------------
#define PLANE (2*H_BAND*W_FULL)
#define CCHUNK 64
__global__ __launch_bounds__(256) void sort_boxes_kernel(
    const float* __restrict__ boxes, int* __restrict__ perm)
{
    __shared__ int keys[NBOX];
    __shared__ int vals[NBOX];
    const int tid = threadIdx.x;
    for (int i = tid; i < NBOX; i += 256) {
        const int n = (int)boxes[i*5 + 0];
        const int y = (int)boxes[i*5 + 2];
        keys[i] = n * 256 + y;
        vals[i] = i;
    }
    __syncthreads();
    for (int size = 2; size <= NBOX; size <<= 1) {
        for (int stride = size >> 1; stride > 0; stride >>= 1) {
            const int i = (tid / stride) * (stride * 2) + (tid % stride);
            const int j = i + stride;
            const bool up = ((i & size) == 0);
            const int ki = keys[i], kj = keys[j];
            if ((ki > kj) == up) {
                keys[i] = kj; keys[j] = ki;
                const int v = vals[i]; vals[i] = vals[j]; vals[j] = v;
            }
            __syncthreads();
        }
    }
    for (int i = tid; i < NBOX; i += 256) perm[i] = vals[i];
}

__global__ __launch_bounds__(256) void roi_align_fallback(
    const float* __restrict__ feat, const float* __restrict__ boxes,
    const int* __restrict__ perm, float* __restrict__ out)
{
    __shared__ int    f_i0[NS];
    __shared__ int    f_i1[NS];
    __shared__ float4 f_w[NS];
    const int b     = blockIdx.x;
    const int jj    = b & 7;
    const int chunk = jj & 3;
    const int band  = jj >> 2;
    const int k     = perm[b >> 3];
    const int tid   = threadIdx.x;
    const float bxf = boxes[k*5+0], x1 = boxes[k*5+1], y1 = boxes[k*5+2];
    const float x2  = boxes[k*5+3], y2 = boxes[k*5+4];
    const int   n   = (int)bxf;
    const float bin_w = fmaxf(x2 - x1, 1.0f) * (1.0f/7.0f);
    const float bin_h = fmaxf(y2 - y1, 1.0f) * (1.0f/7.0f);
    if (tid < NS) {
        const int sy = tid / SS, sx = tid - (tid / SS) * SS;
        float y = y1 + ((float)(sy>>1) + ((float)(sy&1) + 0.5f) * 0.5f) * bin_h;
        float x = x1 + ((float)(sx>>1) + ((float)(sx&1) + 0.5f) * 0.5f) * bin_w;
        const bool valid = (y >= -1.f) && (y <= 100.f) && (x >= -1.f) && (x <= 200.f);
        y = fminf(fmaxf(y, 0.f), 99.f);
        x = fminf(fmaxf(x, 0.f), 199.f);
        const int y_lo = (int)floorf(y), x_lo = (int)floorf(x);
        const int y_hi = min(y_lo + 1, H_BAND - 1);
        const float ly = y - (float)y_lo, lx = x - (float)x_lo;
        const float hy = 1.f - ly, hx = 1.f - lx;
        const int xb = min(x_lo, W_FULL - 2);
        float w0, w1;
        if (x_lo == xb) { w0 = hx; w1 = lx; } else { w0 = 0.f; w1 = hx + lx; }
        const float vs = valid ? 1.f : 0.f;
        f_i0[tid] = y_lo * W_FULL + xb;
        f_i1[tid] = y_hi * W_FULL + xb;
        f_w[tid] = make_float4(hy*w0*vs, hy*w1*vs, ly*w0*vs, ly*w1*vs);
    }
    __syncthreads();
    const int c0 = chunk * CCHUNK;
    const float* fbase = feat + (size_t)(n * C_BAND + c0) * PLANE
                              + (size_t)band * (H_BAND * W_FULL);
    float* obase = out + ((size_t)k * (2*C_BAND) + (size_t)band * C_BAND + c0) * 49;
    for (int o = tid; o < CCHUNK * 49; o += 256) {
        const int c = o / 49, bin = o - (o / 49) * 49;
        const int ph = bin / 7, pw = bin - (bin / 7) * 7;
        const float* fc = fbase + (size_t)c * PLANE;
        const int s00 = (ph * 2) * SS + pw * 2;
        float acc = 0.f;
        #pragma unroll
        for (int iy = 0; iy < 2; ++iy)
        #pragma unroll
        for (int ix = 0; ix < 2; ++ix) {
            const int s = s00 + iy * SS + ix;
            const float4 w = f_w[s];
            const float2 a = *(const float2*)(fc + f_i0[s]);
            const float2 d = *(const float2*)(fc + f_i1[s]);
            acc += w.x * a.x + w.y * a.y + w.z * d.x + w.w * d.y;
        }
        obase[o] = acc * 0.25f;
    }
}

extern "C" void kernel_launch(void* const* d_in, const int* in_sizes, int n_in,
                              void* d_out, int out_size, void* d_ws, size_t ws_size,
                              hipStream_t stream) {
    const float* feat  = (const float*)d_in[0];   // [4,256,200,200] f32
    const float* boxes = (const float*)d_in[1];   // [512,5] f32
    float* out = (float*)d_out;                   // [512,512,7,7] f32
    int* perm = (int*)d_ws;                       // 512 ints = 2048 B

    const size_t needT = FEATT_OFF
        + (size_t)4 * POS * C_BAND * sizeof(unsigned short);   // ~82 MB
    if (ws_size >= needT) {
        unsigned short* featT = (unsigned short*)((char*)d_ws + FEATT_OFF);
        transpose_sort_kernel<<<10000, 256, 0, stream>>>(feat, featT, boxes, perm);
        roi_gather_kernel<<<1024, 256, 0, stream>>>(featT, boxes, perm, out);
    } else {
        sort_boxes_kernel<<<1, 256, 0, stream>>>(boxes, perm);
        roi_align_fallback<<<NBOX * 8, 256, 0, stream>>>(feat, boxes, perm, out);
    }
}